// Round 14
// baseline (230.922 us; speedup 1.0000x reference)
//
#include <hip/hip_runtime.h>
#include <hip/hip_bf16.h>

// B=4, S=2048, D=1024; fp32 in/out, bf16 MFMA compute.
// R14 = R11/R13 base; MODE 0 (fused fp32 proj) restructured as T14 async-split:
// A reg-staged fp32 (issue loads for k+1 BEFORE compute k), cvt+ds_write into
// double-buffered As AFTER compute, raw s_barrier + counted vmcnt ledger:
//   top: [4B older, 8A newer] VMW(8) drains B;  post: [8A older, 4B newer]
//   VMW(4) drains A.  B keeps gload_lds single-buffer (m97 pattern).
#define SS 2048
#define DD 1024
#define NB 4

typedef __attribute__((ext_vector_type(8))) short  bf8;    // 8 x bf16
typedef __attribute__((ext_vector_type(4))) float  f32x4;

static __device__ __forceinline__ unsigned short f2bf(float f) {
    unsigned u = __float_as_uint(f);
    u += 0x7fffu + ((u >> 16) & 1u);          // round-to-nearest-even
    return (unsigned short)(u >> 16);
}
static __device__ __forceinline__ float bf2f(unsigned short u) {
    return __uint_as_float((unsigned)u << 16);
}
static __device__ __forceinline__ unsigned short f2bf_hw(float f) {
    union { __hip_bfloat16 h; unsigned short s; } u;
    u.h = __float2bfloat16(f);                // HW v_cvt (RNE), compiler packs
    return u.s;
}

static __device__ __forceinline__ void gload_lds16(const void* g, void* lds) {
    __builtin_amdgcn_global_load_lds((__attribute__((address_space(1))) void*)g,
                                     (__attribute__((address_space(3))) void*)lds,
                                     16, 0, 0);
}

#define BARM()  asm volatile("s_barrier" ::: "memory")
#define LGKM0() asm volatile("s_waitcnt lgkmcnt(0)" ::: "memory")
#define VMW(N)  asm volatile("s_waitcnt vmcnt(" #N ")" ::: "memory")

// ---------------- fp32 -> bf16 convert (weights only) ----------------
__global__ __launch_bounds__(256)
void cvt3(const float* __restrict__ a, const float* __restrict__ b, const float* __restrict__ c,
          unsigned short* __restrict__ oa, unsigned short* __restrict__ ob,
          unsigned short* __restrict__ oc, int n4) {
    int i = blockIdx.x * 256 + threadIdx.x;
    if (i >= n4) return;
    const float* in = blockIdx.y == 0 ? a : blockIdx.y == 1 ? b : c;
    unsigned short* out = blockIdx.y == 0 ? oa : blockIdx.y == 1 ? ob : oc;
    float4 v = ((const float4*)in)[i];
    ushort4 o;
    o.x = f2bf(v.x); o.y = f2bf(v.y); o.z = f2bf(v.z); o.w = f2bf(v.w);
    ((ushort4*)out)[i] = o;
}

// ---------------- 128x128 BK=64 bt-GEMM, T2-swizzled LDS ----------------
// MODE 0: merged QKV proj, A = fp32 async reg-staged+cvt, As double-buffered
// MODE 2: scores = Q.K^T/32 -> bf16, exact triangular grid (flat 544)
// MODE 3: PV, fp32 out, causal K-limit, balanced-triple flat grid (768)
#define BM 128
#define BN 128
#define BK 64

template<int MODE>
__global__ __launch_bounds__(256, 3)
void gemm_bt(const void* __restrict__ A0v, const unsigned short* __restrict__ B0p,
             const float* __restrict__ bias0,
             const void* __restrict__ A1v, const unsigned short* __restrict__ B1p,
             const float* __restrict__ bias1,
             const void* __restrict__ A2v, const unsigned short* __restrict__ B2p,
             const float* __restrict__ bias2,
             void* __restrict__ Cout)
{
    constexpr int LDA = (MODE == 3) ? 2048 : 1024;
    constexpr int LDB = (MODE == 3) ? 2048 : 1024;

    int bx, by, bz;
    int qt = 0, nsp = 1, seg = 0;
    if (MODE == 2) {
        int f  = (int)blockIdx.x;
        int f2 = (f & 7) * 68 + (f >> 3);
        bz = f2 / 136;
        int r = f2 - bz * 136;
        by = (int)((__fsqrt_rn(8.f * (float)r + 1.f) - 1.f) * 0.5f);
        if (by > 15) by = 15;
        while ((by + 1) * (by + 2) / 2 <= r) ++by;
        while (by * (by + 1) / 2 > r) --by;
        bx = r - by * (by + 1) / 2;
    } else if (MODE == 3) {
        constexpr unsigned long long T0 = 7ull | 63ull << 6 | 46ull << 12 | 62ull << 18 |
                                          45ull << 24 | 61ull << 30 | 60ull << 36 | 43ull << 42;
        constexpr unsigned long long T1 = 47ull | 6ull << 6 | 44ull << 12 | 42ull << 18 |
                                          4ull << 24 | 58ull << 30 | 5ull << 36 | 59ull << 42;
        constexpr unsigned long long T2 = 0ull | 1ull << 6 | 2ull << 12 | 3ull << 18 |
                                          41ull << 24 | 40ull << 30 | 56ull << 36 | 57ull << 42;
        int f = (int)blockIdx.x;
        int layer = f >> 8, ti = f & 255;
        bz = ti >> 6;
        bx = (ti >> 3) & 7;
        int t = ti & 7;
        unsigned long long tab = layer == 0 ? T0 : layer == 1 ? T1 : T2;
        int e = (int)((tab >> (t * 6)) & 63);
        qt  = e & 15;
        seg = (e >> 4) & 1;
        nsp = ((e >> 5) & 1) ? 2 : 1;
        by  = 0;
    } else {
        constexpr int GX  = 8;
        constexpr int CPX = 512 >> 3;
        int f  = (int)blockIdx.y * GX + (int)blockIdx.x;
        int f2 = (f & 7) * CPX + (f >> 3);
        bx = f2 % GX; by = f2 / GX;
        bz = blockIdx.z;
    }

    const float* Af = nullptr;
    const unsigned short* Ab = nullptr;
    const unsigned short* Bm;
    const float* bias = nullptr;
    int len;
    if (MODE == 0) {
        Af   = ((const float*)(bz == 0 ? A0v : bz == 1 ? A1v : A2v)) + (size_t)by * BM * LDA;
        Bm   = (bz == 0 ? B0p : bz == 1 ? B1p : B2p) + (size_t)bx * BN * LDB;
        bias = bz == 0 ? bias0 : bz == 1 ? bias1 : bias2;
        len  = 1024;
    } else if (MODE == 2) {
        Ab  = (const unsigned short*)A0v + (size_t)bz * SS * DD + (size_t)by * BM * LDA;
        Bm  = B0p + (size_t)bz * SS * DD + (size_t)bx * BN * LDB;
        len = 1024;
    } else {
        int ktot = (qt + 1) * 128, hk = ktot >> 1;
        int kst  = (nsp == 2 && seg) ? hk : 0;
        len = (nsp == 1) ? ktot : hk;
        Ab = (const unsigned short*)A0v + (size_t)bz * SS * SS + (size_t)qt * BM * LDA + kst;
        Bm = B0p + (size_t)bz * DD * SS + (size_t)bx * BN * LDB + kst;
    }

    // LDS: MODE 0 = As dbuf 2x16KB + Bs 16KB = 48KB; else As 16KB + Bs 16KB
    constexpr int ABYTES = (MODE == 0) ? 32768 : 16384;
    __shared__ __align__(16) char AsB[ABYTES];
    __shared__ __align__(16) unsigned short Bs[BN * BK];

    const int t = threadIdx.x;
    const int l = t & 63;
    const int w = t >> 6;
    const int wr = w >> 1, wc = w & 1;

    const int srow0 = t >> 3;
    const int sswz  = (t & 7) ^ ((t >> 3) & 7);
    const int j0 = l >> 4;
    const int ar = wr * 64 + (l & 15);
    const int br = wc * 64 + (l & 15);

    f32x4 zero = {0.f, 0.f, 0.f, 0.f};
    f32x4 acc[4][4];
    #pragma unroll
    for (int i = 0; i < 4; i++)
        #pragma unroll
        for (int j = 0; j < 4; j++) acc[i][j] = zero;

    if (MODE == 0) {
        // reg-staging geometry: thread owns row t>>1, 32-col half t&1
        const int arow  = t >> 1;
        const int ahalf = t & 1;
        const int arsz  = arow & 7;
        const float* arowp = Af + (size_t)arow * LDA + ahalf * 32;
        char* As0 = AsB;                     // double buffer
        f32x4 av[8];

        // ---- prologue: stage tile 0 ----
        #pragma unroll
        for (int i = 0; i < 8; ++i) av[i] = *(const f32x4*)(arowp + i * 4);
        #pragma unroll
        for (int j = 0; j < 4; ++j) {
            int r = srow0 + 32 * j;
            gload_lds16(Bm + (size_t)r * LDB + sswz * 8,
                        (char*)Bs + (t + 256 * j) * 16);
        }
        VMW(4);     // drain 8 A-reg loads (oldest); 4 B remain in flight
        #pragma unroll
        for (int i = 0; i < 4; ++i) {
            f32x4 lo = av[2 * i], hi = av[2 * i + 1];
            bf8 vv;
            vv[0] = (short)f2bf_hw(lo[0]); vv[1] = (short)f2bf_hw(lo[1]);
            vv[2] = (short)f2bf_hw(lo[2]); vv[3] = (short)f2bf_hw(lo[3]);
            vv[4] = (short)f2bf_hw(hi[0]); vv[5] = (short)f2bf_hw(hi[1]);
            vv[6] = (short)f2bf_hw(hi[2]); vv[7] = (short)f2bf_hw(hi[3]);
            int c = (ahalf * 4 + i) ^ arsz;
            *(bf8*)(As0 + (size_t)arow * 128 + c * 16) = vv;
        }
        LGKM0();

        int cur = 0;
        for (int kk = 0; kk < len; kk += BK) {
            int kkn = (kk + BK < len) ? kk + BK : kk;   // clamp: last iter restages
            // issue A-reg loads for next tile (BEFORE compute)
            #pragma unroll
            for (int i = 0; i < 8; ++i) av[i] = *(const f32x4*)(arowp + kkn + i * 4);
            VMW(8);   // drain 4 B (oldest); 8 A-regs remain
            BARM();   // Bs + As[cur] ready for all waves
            {
                const char* Ac = AsB + cur * 16384;
                #pragma unroll
                for (int ks = 0; ks < 2; ++ks) {
                    bf8 af[4], bfr[4];
                    #pragma unroll
                    for (int i = 0; i < 4; i++) {
                        int r = ar + i * 16;
                        af[i] = *(const bf8*)(Ac + (size_t)r * 128 +
                                              (((j0 + ks * 4) ^ (r & 7)) << 4));
                    }
                    #pragma unroll
                    for (int j = 0; j < 4; j++) {
                        int r = br + j * 16;
                        bfr[j] = *(const bf8*)((char*)Bs + (size_t)r * 128 +
                                               (((j0 + ks * 4) ^ (r & 7)) << 4));
                    }
                    #pragma unroll
                    for (int i = 0; i < 4; i++)
                        #pragma unroll
                        for (int j = 0; j < 4; j++)
                            acc[i][j] = __builtin_amdgcn_mfma_f32_16x16x32_bf16(af[i], bfr[j], acc[i][j], 0, 0, 0);
                }
            }
            BARM();   // all waves done reading Bs and As[cur]
            // stage B(next) into Bs (safe now)
            #pragma unroll
            for (int j = 0; j < 4; ++j) {
                int r = srow0 + 32 * j;
                gload_lds16(Bm + (size_t)r * LDB + kkn + sswz * 8,
                            (char*)Bs + (t + 256 * j) * 16);
            }
            VMW(4);   // drain 8 A-regs (oldest); 4 B remain
            // cvt + write into other A buffer (last read 2 barriers ago)
            char* An = AsB + (cur ^ 1) * 16384;
            #pragma unroll
            for (int i = 0; i < 4; ++i) {
                f32x4 lo = av[2 * i], hi = av[2 * i + 1];
                bf8 vv;
                vv[0] = (short)f2bf_hw(lo[0]); vv[1] = (short)f2bf_hw(lo[1]);
                vv[2] = (short)f2bf_hw(lo[2]); vv[3] = (short)f2bf_hw(lo[3]);
                vv[4] = (short)f2bf_hw(hi[0]); vv[5] = (short)f2bf_hw(hi[1]);
                vv[6] = (short)f2bf_hw(hi[2]); vv[7] = (short)f2bf_hw(hi[3]);
                int c = (ahalf * 4 + i) ^ arsz;
                *(bf8*)(An + (size_t)arow * 128 + c * 16) = vv;
            }
            LGKM0();
            cur ^= 1;
        }

        // ---- epilogue/store ----
        const int mb = by * BM + wr * 64;
        const int nb = bx * BN + wc * 64;
        float bv[4];
        #pragma unroll
        for (int j = 0; j < 4; j++) bv[j] = bias[nb + j * 16 + (l & 15)];
        if (bz < 2) {
            unsigned short* C = (unsigned short*)Cout + (size_t)bz * NB * SS * DD;
            #pragma unroll
            for (int i = 0; i < 4; i++) {
                int m0 = mb + i * 16 + ((l >> 4) << 2);
                #pragma unroll
                for (int j = 0; j < 4; j++) {
                    int n = nb + j * 16 + (l & 15);
                    #pragma unroll
                    for (int r = 0; r < 4; r++)
                        C[(size_t)(m0 + r) * DD + n] = f2bf(acc[i][j][r] + bv[j]);
                }
            }
        } else {
            unsigned short* C = (unsigned short*)Cout + (size_t)2 * NB * SS * DD;
            int batch = (by * BM) >> 11;
            #pragma unroll
            for (int i = 0; i < 4; i++) {
                int s = (mb - batch * SS) + i * 16 + ((l >> 4) << 2);
                #pragma unroll
                for (int j = 0; j < 4; j++) {
                    int n = nb + j * 16 + (l & 15);
                    ushort4 pk;
                    pk.x = f2bf(acc[i][j][0] + bv[j]);
                    pk.y = f2bf(acc[i][j][1] + bv[j]);
                    pk.z = f2bf(acc[i][j][2] + bv[j]);
                    pk.w = f2bf(acc[i][j][3] + bv[j]);
                    *(ushort4*)&C[(size_t)batch * DD * SS + (size_t)n * SS + s] = pk;
                }
            }
        }
        return;
    }

    // ---- MODE 2/3: proven path (unchanged) ----
    for (int kk = 0; kk < len; kk += BK) {
        #pragma unroll
        for (int j = 0; j < 4; ++j) {
            int r = srow0 + 32 * j;
            gload_lds16(Ab + (size_t)r * LDA + kk + sswz * 8,
                        AsB + (t + 256 * j) * 16);
            gload_lds16(Bm + (size_t)r * LDB + kk + sswz * 8,
                        (char*)Bs + (t + 256 * j) * 16);
        }
        __syncthreads();
        #pragma unroll
        for (int ks = 0; ks < 2; ++ks) {
            bf8 af[4], bfr[4];
            #pragma unroll
            for (int i = 0; i < 4; i++) {
                int r = ar + i * 16;
                af[i] = *(const bf8*)(AsB + (size_t)r * 128 +
                                      (((j0 + ks * 4) ^ (r & 7)) << 4));
            }
            #pragma unroll
            for (int j = 0; j < 4; j++) {
                int r = br + j * 16;
                bfr[j] = *(const bf8*)((char*)Bs + (size_t)r * 128 +
                                       (((j0 + ks * 4) ^ (r & 7)) << 4));
            }
            #pragma unroll
            for (int i = 0; i < 4; i++)
                #pragma unroll
                for (int j = 0; j < 4; j++)
                    acc[i][j] = __builtin_amdgcn_mfma_f32_16x16x32_bf16(af[i], bfr[j], acc[i][j], 0, 0, 0);
        }
        __syncthreads();
    }

    const int mb = ((MODE == 3) ? qt : by) * BM + wr * 64;
    const int nb = bx * BN + wc * 64;

    if (MODE == 2) {
        unsigned short* C = (unsigned short*)Cout + (size_t)bz * SS * SS;
        #pragma unroll
        for (int i = 0; i < 4; i++) {
            int m0 = mb + i * 16 + ((l >> 4) << 2);
            #pragma unroll
            for (int j = 0; j < 4; j++) {
                int n = nb + j * 16 + (l & 15);
                #pragma unroll
                for (int r = 0; r < 4; r++)
                    C[(size_t)(m0 + r) * SS + n] = f2bf(acc[i][j][r] * 0.03125f);
            }
        }
    } else {
        float* C = (float*)Cout + (size_t)bz * SS * DD;
        #pragma unroll
        for (int i = 0; i < 4; i++) {
            int m0 = mb + i * 16 + ((l >> 4) << 2);
            #pragma unroll
            for (int j = 0; j < 4; j++) {
                int n = nb + j * 16 + (l & 15);
                if (nsp == 1) {
                    #pragma unroll
                    for (int r = 0; r < 4; r++)
                        C[(size_t)(m0 + r) * DD + n] = acc[i][j][r];
                } else {
                    #pragma unroll
                    for (int r = 0; r < 4; r++)
                        atomicAdd(&C[(size_t)(m0 + r) * DD + n], acc[i][j][r]);
                }
            }
        }
    }
}

// ---------------- causal row softmax: bf16 scores -> bf16 P ----------------
__global__ __launch_bounds__(256)
void softmax_causal(const unsigned short* __restrict__ Sb, unsigned short* __restrict__ P) {
    __shared__ float tm[4], tl[4];
    int row = blockIdx.x;
    int b = row >> 11, q = row & 2047;
    const unsigned short* s = Sb + ((size_t)b * SS + q) * SS;
    unsigned short* p = P + ((size_t)b * SS + q) * SS;
    int len  = q + 1;
    int len8 = len >> 3;
    int wlen = ((q >> 7) + 1) << 7;

    float m = -3e38f, lsum = 0.f;
    for (int i8 = threadIdx.x; i8 < len8; i8 += 256) {
        ushort4 u0 = ((const ushort4*)s)[i8 * 2];
        ushort4 u1 = ((const ushort4*)s)[i8 * 2 + 1];
        float v[8] = {bf2f(u0.x), bf2f(u0.y), bf2f(u0.z), bf2f(u0.w),
                      bf2f(u1.x), bf2f(u1.y), bf2f(u1.z), bf2f(u1.w)};
        float cm = v[0];
        #pragma unroll
        for (int e = 1; e < 8; ++e) cm = fmaxf(cm, v[e]);
        float cs = 0.f;
        #pragma unroll
        for (int e = 0; e < 8; ++e) cs += __expf(v[e] - cm);
        float nm = fmaxf(m, cm);
        lsum = lsum * __expf(m - nm) + cs * __expf(cm - nm);
        m = nm;
    }
    for (int i = (len8 << 3) + threadIdx.x; i < len; i += 256) {
        float v = bf2f(s[i]);
        float nm = fmaxf(m, v);
        lsum = lsum * __expf(m - nm) + __expf(v - nm);
        m = nm;
    }
    #pragma unroll
    for (int o = 32; o; o >>= 1) {
        float om = __shfl_xor(m, o);
        float ol = __shfl_xor(lsum, o);
        float nm = fmaxf(m, om);
        lsum = lsum * __expf(m - nm) + ol * __expf(om - nm);
        m = nm;
    }
    if ((threadIdx.x & 63) == 0) { tm[threadIdx.x >> 6] = m; tl[threadIdx.x >> 6] = lsum; }
    __syncthreads();
    {
        float gm = fmaxf(fmaxf(tm[0], tm[1]), fmaxf(tm[2], tm[3]));
        float gl = tl[0] * __expf(tm[0] - gm) + tl[1] * __expf(tm[1] - gm)
                 + tl[2] * __expf(tm[2] - gm) + tl[3] * __expf(tm[3] - gm);
        m = gm; lsum = gl;
    }
    float inv = 1.f / lsum;

    for (int i8 = threadIdx.x; i8 < (wlen >> 3); i8 += 256) {
        int i = i8 << 3;
        ushort4 u0 = ((const ushort4*)s)[i8 * 2];
        ushort4 u1 = ((const ushort4*)s)[i8 * 2 + 1];
        ushort4 o0, o1;
        o0.x = (i     < len) ? f2bf(__expf(bf2f(u0.x) - m) * inv) : (unsigned short)0;
        o0.y = (i + 1 < len) ? f2bf(__expf(bf2f(u0.y) - m) * inv) : (unsigned short)0;
        o0.z = (i + 2 < len) ? f2bf(__expf(bf2f(u0.z) - m) * inv) : (unsigned short)0;
        o0.w = (i + 3 < len) ? f2bf(__expf(bf2f(u0.w) - m) * inv) : (unsigned short)0;
        o1.x = (i + 4 < len) ? f2bf(__expf(bf2f(u1.x) - m) * inv) : (unsigned short)0;
        o1.y = (i + 5 < len) ? f2bf(__expf(bf2f(u1.y) - m) * inv) : (unsigned short)0;
        o1.z = (i + 6 < len) ? f2bf(__expf(bf2f(u1.z) - m) * inv) : (unsigned short)0;
        o1.w = (i + 7 < len) ? f2bf(__expf(bf2f(u1.w) - m) * inv) : (unsigned short)0;
        ((ushort4*)p)[i8 * 2]     = o0;
        ((ushort4*)p)[i8 * 2 + 1] = o1;
    }
}

// ---------------- launch ----------------
extern "C" void kernel_launch(void* const* d_in, const int* in_sizes, int n_in,
                              void* d_out, int out_size, void* d_ws, size_t ws_size,
                              hipStream_t stream) {
    constexpr size_t NX = (size_t)NB * SS * DD;   // 8388608
    constexpr size_t NW = (size_t)DD * DD;        // 1048576

    const float* q   = (const float*)d_in[0];
    const float* k   = (const float*)d_in[1];
    const float* v   = (const float*)d_in[2];
    const float* w_q = (const float*)d_in[4];
    const float* b_q = (const float*)d_in[5];
    const float* w_k = (const float*)d_in[6];
    const float* b_k = (const float*)d_in[7];
    const float* w_v = (const float*)d_in[8];
    const float* b_v = (const float*)d_in[9];
    float* out = (float*)d_out;

    char* ws = (char*)d_ws;
    size_t off = 0;
    auto take = [&](size_t bytes) { char* p = ws + off; off += (bytes + 255) & ~(size_t)255; return p; };
    unsigned short* wqb = (unsigned short*)take(NW * 2);
    unsigned short* wkb = (unsigned short*)take(NW * 2);
    unsigned short* wvb = (unsigned short*)take(NW * 2);
    unsigned short* QKV = (unsigned short*)take(NX * 2 * 3);   // Qp | Kp | VpT
    unsigned short* Sb  = (unsigned short*)take((size_t)NB * SS * SS * 2);
    unsigned short* P   = (unsigned short*)take((size_t)NB * SS * SS * 2);
    unsigned short* Qp  = QKV;
    unsigned short* Kp  = QKV + NX;
    unsigned short* VpT = QKV + 2 * NX;           // [b][d][s]

    dim3 blk(256);
    // PV split-K accumulates only into rows >= 1024 of each batch
    for (int b = 0; b < NB; ++b)
        hipMemsetAsync(out + ((size_t)b * SS + 1024) * DD, 0, (size_t)1024 * DD * 4, stream);
    cvt3<<<dim3(NW / 4 / 256, 3), blk, 0, stream>>>(w_q, w_k, w_v, wqb, wkb, wvb, (int)(NW / 4));

    // merged projections: M=8192, N=1024, K=1024; A = fp32 inputs (fused cvt)
    gemm_bt<0><<<dim3(8, 64, 3), blk, 0, stream>>>(
        q, wqb, b_q, k, wkb, b_k, v, wvb, b_v, QKV);

    // scores: exact triangular grid, 544 = 4 batches x 136 tiles
    gemm_bt<2><<<dim3(544), blk, 0, stream>>>(
        Qp, Kp, nullptr, nullptr, nullptr, nullptr, nullptr, nullptr, nullptr, Sb);

    softmax_causal<<<dim3(NB * SS), blk, 0, stream>>>(Sb, P);

    // PV: balanced-triple flat grid (768 = 3 layers x 256)
    gemm_bt<3><<<dim3(768), blk, 0, stream>>>(
        P, VpT, nullptr, nullptr, nullptr, nullptr, nullptr, nullptr, nullptr, out);
}

// Round 15
// 187.824 us; speedup vs baseline: 1.2295x; 1.2295x over previous
//
#include <hip/hip_runtime.h>
#include <hip/hip_bf16.h>

// B=4, S=2048, D=1024; fp32 in/out, bf16 MFMA compute.
// R15 = R11 config with ONLY the proj A-path swapped back to the proven
// unfused bf16 gload_lds engine (56.5us @ 912 TF) + separate cvt (25us BW);
// dispatch-sum says this beats fused 105us by ~23us. Clean A/B vs R10's
// confounded regression (it also changed PV grid + P placement).
#define SS 2048
#define DD 1024
#define NB 4

typedef __attribute__((ext_vector_type(8))) short  bf8;    // 8 x bf16
typedef __attribute__((ext_vector_type(4))) float  f32x4;

static __device__ __forceinline__ unsigned short f2bf(float f) {
    unsigned u = __float_as_uint(f);
    u += 0x7fffu + ((u >> 16) & 1u);          // round-to-nearest-even
    return (unsigned short)(u >> 16);
}
static __device__ __forceinline__ float bf2f(unsigned short u) {
    return __uint_as_float((unsigned)u << 16);
}

static __device__ __forceinline__ void gload_lds16(const void* g, void* lds) {
    __builtin_amdgcn_global_load_lds((__attribute__((address_space(1))) void*)g,
                                     (__attribute__((address_space(3))) void*)lds,
                                     16, 0, 0);
}

// ---------------- fp32 -> bf16 converts ----------------
__global__ __launch_bounds__(256)
void cvt3(const float* __restrict__ a, const float* __restrict__ b, const float* __restrict__ c,
          unsigned short* __restrict__ oa, unsigned short* __restrict__ ob,
          unsigned short* __restrict__ oc, int n4) {
    int i = blockIdx.x * 256 + threadIdx.x;
    if (i >= n4) return;
    const float* in = blockIdx.y == 0 ? a : blockIdx.y == 1 ? b : c;
    unsigned short* out = blockIdx.y == 0 ? oa : blockIdx.y == 1 ? ob : oc;
    float4 v = ((const float4*)in)[i];
    ushort4 o;
    o.x = f2bf(v.x); o.y = f2bf(v.y); o.z = f2bf(v.z); o.w = f2bf(v.w);
    ((ushort4*)out)[i] = o;
}

// ---------------- 128x128 BK=64 bt-GEMM, T2-swizzled LDS ----------------
// MODE 0: merged QKV proj (bf16 A); z = which proj; z==2 -> transposed store
// MODE 2: scores = Q.K^T/32 -> bf16, exact triangular grid (flat 544)
// MODE 3: PV, fp32 out, causal K-limit, balanced-triple flat grid (768)
#define BM 128
#define BN 128
#define BK 64

template<int MODE>
__global__ __launch_bounds__(256, 3)
void gemm_bt(const void* __restrict__ A0v, const unsigned short* __restrict__ B0p,
             const float* __restrict__ bias0,
             const void* __restrict__ A1v, const unsigned short* __restrict__ B1p,
             const float* __restrict__ bias1,
             const void* __restrict__ A2v, const unsigned short* __restrict__ B2p,
             const float* __restrict__ bias2,
             void* __restrict__ Cout)
{
    constexpr int LDA = (MODE == 3) ? 2048 : 1024;
    constexpr int LDB = (MODE == 3) ? 2048 : 1024;

    int bx, by, bz;
    int qt = 0, nsp = 1, seg = 0;
    if (MODE == 2) {
        // flat 544 = 8*68; bijective XCD chunking, triangular decode
        int f  = (int)blockIdx.x;
        int f2 = (f & 7) * 68 + (f >> 3);
        bz = f2 / 136;
        int r = f2 - bz * 136;
        by = (int)((__fsqrt_rn(8.f * (float)r + 1.f) - 1.f) * 0.5f);
        if (by > 15) by = 15;
        while ((by + 1) * (by + 2) / 2 <= r) ++by;
        while (by * (by + 1) / 2 > r) --by;
        bx = r - by * (by + 1) / 2;
    } else if (MODE == 3) {
        // balanced triples: 3 layers x 256 (b,xt,t); each triple = 2176 rows
        constexpr unsigned long long T0 = 7ull | 63ull << 6 | 46ull << 12 | 62ull << 18 |
                                          45ull << 24 | 61ull << 30 | 60ull << 36 | 43ull << 42;
        constexpr unsigned long long T1 = 47ull | 6ull << 6 | 44ull << 12 | 42ull << 18 |
                                          4ull << 24 | 58ull << 30 | 5ull << 36 | 59ull << 42;
        constexpr unsigned long long T2 = 0ull | 1ull << 6 | 2ull << 12 | 3ull << 18 |
                                          41ull << 24 | 40ull << 30 | 56ull << 36 | 57ull << 42;
        int f = (int)blockIdx.x;              // 0..767
        int layer = f >> 8, ti = f & 255;
        bz = ti >> 6;
        bx = (ti >> 3) & 7;
        int t = ti & 7;
        unsigned long long tab = layer == 0 ? T0 : layer == 1 ? T1 : T2;
        int e = (int)((tab >> (t * 6)) & 63);
        qt  = e & 15;
        seg = (e >> 4) & 1;
        nsp = ((e >> 5) & 1) ? 2 : 1;
        by  = 0;
    } else {
        constexpr int GX  = 8;
        constexpr int CPX = 512 >> 3;
        int f  = (int)blockIdx.y * GX + (int)blockIdx.x;
        int f2 = (f & 7) * CPX + (f >> 3);
        bx = f2 % GX; by = f2 / GX;
        bz = blockIdx.z;
    }

    const unsigned short* Ab;
    const unsigned short* Bm;
    const float* bias = nullptr;
    int len;
    if (MODE == 0) {
        Ab   = ((const unsigned short*)(bz == 0 ? A0v : bz == 1 ? A1v : A2v)) + (size_t)by * BM * LDA;
        Bm   = (bz == 0 ? B0p : bz == 1 ? B1p : B2p) + (size_t)bx * BN * LDB;
        bias = bz == 0 ? bias0 : bz == 1 ? bias1 : bias2;
        len  = 1024;
    } else if (MODE == 2) {
        Ab  = (const unsigned short*)A0v + (size_t)bz * SS * DD + (size_t)by * BM * LDA;
        Bm  = B0p + (size_t)bz * SS * DD + (size_t)bx * BN * LDB;
        len = 1024;
    } else {
        int ktot = (qt + 1) * 128, hk = ktot >> 1;       // hk multiple of 64
        int kst  = (nsp == 2 && seg) ? hk : 0;
        len = (nsp == 1) ? ktot : hk;
        Ab = (const unsigned short*)A0v + (size_t)bz * SS * SS + (size_t)qt * BM * LDA + kst;
        Bm = B0p + (size_t)bz * DD * SS + (size_t)bx * BN * LDB + kst;
    }

    __shared__ __align__(16) unsigned short As[BM * BK];   // 16 KB, swizzled
    __shared__ __align__(16) unsigned short Bs[BN * BK];

    const int t = threadIdx.x;
    const int l = t & 63;
    const int w = t >> 6;
    const int wr = w >> 1, wc = w & 1;

    // staging: LDS[r][s] = G[r][s ^ (r&7)] (16B-chunk involution; reads undo)
    const int srow0 = t >> 3;
    const int sswz  = (t & 7) ^ ((t >> 3) & 7);

    f32x4 zero = {0.f, 0.f, 0.f, 0.f};
    f32x4 acc[4][4];
    #pragma unroll
    for (int i = 0; i < 4; i++)
        #pragma unroll
        for (int j = 0; j < 4; j++) acc[i][j] = zero;

    const int ar = wr * 64 + (l & 15);          // A fragment row
    const int br = wc * 64 + (l & 15);          // B fragment row (output col)
    const int j0 = l >> 4;                      // base chunk (ks adds 4)

    for (int kk = 0; kk < len; kk += BK) {
        #pragma unroll
        for (int j = 0; j < 4; ++j) {
            int r = srow0 + 32 * j;
            gload_lds16(Ab + (size_t)r * LDA + kk + sswz * 8,
                        (char*)As + (t + 256 * j) * 16);
            gload_lds16(Bm + (size_t)r * LDB + kk + sswz * 8,
                        (char*)Bs + (t + 256 * j) * 16);
        }
        __syncthreads();
        #pragma unroll
        for (int ks = 0; ks < 2; ++ks) {
            bf8 af[4], bfr[4];
            #pragma unroll
            for (int i = 0; i < 4; i++) {
                int r = ar + i * 16;
                af[i] = *(const bf8*)((char*)As + (size_t)r * 128 +
                                      (((j0 + ks * 4) ^ (r & 7)) << 4));
            }
            #pragma unroll
            for (int j = 0; j < 4; j++) {
                int r = br + j * 16;
                bfr[j] = *(const bf8*)((char*)Bs + (size_t)r * 128 +
                                       (((j0 + ks * 4) ^ (r & 7)) << 4));
            }
            #pragma unroll
            for (int i = 0; i < 4; i++)
                #pragma unroll
                for (int j = 0; j < 4; j++)
                    acc[i][j] = __builtin_amdgcn_mfma_f32_16x16x32_bf16(af[i], bfr[j], acc[i][j], 0, 0, 0);
        }
        __syncthreads();
    }

    const int mb = ((MODE == 3) ? qt : by) * BM + wr * 64;
    const int nb = bx * BN + wc * 64;

    if (MODE == 0) {
        float bv[4];
        #pragma unroll
        for (int j = 0; j < 4; j++) bv[j] = bias[nb + j * 16 + (l & 15)];
        if (bz < 2) {
            unsigned short* C = (unsigned short*)Cout + (size_t)bz * NB * SS * DD;
            #pragma unroll
            for (int i = 0; i < 4; i++) {
                int m0 = mb + i * 16 + ((l >> 4) << 2);
                #pragma unroll
                for (int j = 0; j < 4; j++) {
                    int n = nb + j * 16 + (l & 15);
                    #pragma unroll
                    for (int r = 0; r < 4; r++)
                        C[(size_t)(m0 + r) * DD + n] = f2bf(acc[i][j][r] + bv[j]);
                }
            }
        } else {
            // V: per-batch transposed store C[b][n][s]
            unsigned short* C = (unsigned short*)Cout + (size_t)2 * NB * SS * DD;
            int batch = (by * BM) >> 11;
            #pragma unroll
            for (int i = 0; i < 4; i++) {
                int s = (mb - batch * SS) + i * 16 + ((l >> 4) << 2);
                #pragma unroll
                for (int j = 0; j < 4; j++) {
                    int n = nb + j * 16 + (l & 15);
                    ushort4 pk;
                    pk.x = f2bf(acc[i][j][0] + bv[j]);
                    pk.y = f2bf(acc[i][j][1] + bv[j]);
                    pk.z = f2bf(acc[i][j][2] + bv[j]);
                    pk.w = f2bf(acc[i][j][3] + bv[j]);
                    *(ushort4*)&C[(size_t)batch * DD * SS + (size_t)n * SS + s] = pk;
                }
            }
        }
    } else if (MODE == 2) {
        unsigned short* C = (unsigned short*)Cout + (size_t)bz * SS * SS;
        #pragma unroll
        for (int i = 0; i < 4; i++) {
            int m0 = mb + i * 16 + ((l >> 4) << 2);
            #pragma unroll
            for (int j = 0; j < 4; j++) {
                int n = nb + j * 16 + (l & 15);
                #pragma unroll
                for (int r = 0; r < 4; r++)
                    C[(size_t)(m0 + r) * SS + n] = f2bf(acc[i][j][r] * 0.03125f);
            }
        }
    } else {
        float* C = (float*)Cout + (size_t)bz * SS * DD;
        #pragma unroll
        for (int i = 0; i < 4; i++) {
            int m0 = mb + i * 16 + ((l >> 4) << 2);
            #pragma unroll
            for (int j = 0; j < 4; j++) {
                int n = nb + j * 16 + (l & 15);
                if (nsp == 1) {
                    #pragma unroll
                    for (int r = 0; r < 4; r++)
                        C[(size_t)(m0 + r) * DD + n] = acc[i][j][r];
                } else {
                    #pragma unroll
                    for (int r = 0; r < 4; r++)
                        atomicAdd(&C[(size_t)(m0 + r) * DD + n], acc[i][j][r]);
                }
            }
        }
    }
}

// ---------------- causal row softmax: bf16 scores -> bf16 P ----------------
__global__ __launch_bounds__(256)
void softmax_causal(const unsigned short* __restrict__ Sb, unsigned short* __restrict__ P) {
    __shared__ float tm[4], tl[4];
    int row = blockIdx.x;
    int b = row >> 11, q = row & 2047;
    const unsigned short* s = Sb + ((size_t)b * SS + q) * SS;
    unsigned short* p = P + ((size_t)b * SS + q) * SS;
    int len  = q + 1;
    int len8 = len >> 3;
    int wlen = ((q >> 7) + 1) << 7;            // zero-pad to 128 for PV tiles

    float m = -3e38f, lsum = 0.f;
    for (int i8 = threadIdx.x; i8 < len8; i8 += 256) {
        ushort4 u0 = ((const ushort4*)s)[i8 * 2];
        ushort4 u1 = ((const ushort4*)s)[i8 * 2 + 1];
        float v[8] = {bf2f(u0.x), bf2f(u0.y), bf2f(u0.z), bf2f(u0.w),
                      bf2f(u1.x), bf2f(u1.y), bf2f(u1.z), bf2f(u1.w)};
        float cm = v[0];
        #pragma unroll
        for (int e = 1; e < 8; ++e) cm = fmaxf(cm, v[e]);
        float cs = 0.f;
        #pragma unroll
        for (int e = 0; e < 8; ++e) cs += __expf(v[e] - cm);
        float nm = fmaxf(m, cm);
        lsum = lsum * __expf(m - nm) + cs * __expf(cm - nm);
        m = nm;
    }
    for (int i = (len8 << 3) + threadIdx.x; i < len; i += 256) {
        float v = bf2f(s[i]);
        float nm = fmaxf(m, v);
        lsum = lsum * __expf(m - nm) + __expf(v - nm);
        m = nm;
    }
    #pragma unroll
    for (int o = 32; o; o >>= 1) {
        float om = __shfl_xor(m, o);
        float ol = __shfl_xor(lsum, o);
        float nm = fmaxf(m, om);
        lsum = lsum * __expf(m - nm) + ol * __expf(om - nm);
        m = nm;
    }
    if ((threadIdx.x & 63) == 0) { tm[threadIdx.x >> 6] = m; tl[threadIdx.x >> 6] = lsum; }
    __syncthreads();
    {
        float gm = fmaxf(fmaxf(tm[0], tm[1]), fmaxf(tm[2], tm[3]));
        float gl = tl[0] * __expf(tm[0] - gm) + tl[1] * __expf(tm[1] - gm)
                 + tl[2] * __expf(tm[2] - gm) + tl[3] * __expf(tm[3] - gm);
        m = gm; lsum = gl;
    }
    float inv = 1.f / lsum;

    for (int i8 = threadIdx.x; i8 < (wlen >> 3); i8 += 256) {
        int i = i8 << 3;
        ushort4 u0 = ((const ushort4*)s)[i8 * 2];
        ushort4 u1 = ((const ushort4*)s)[i8 * 2 + 1];
        ushort4 o0, o1;
        o0.x = (i     < len) ? f2bf(__expf(bf2f(u0.x) - m) * inv) : (unsigned short)0;
        o0.y = (i + 1 < len) ? f2bf(__expf(bf2f(u0.y) - m) * inv) : (unsigned short)0;
        o0.z = (i + 2 < len) ? f2bf(__expf(bf2f(u0.z) - m) * inv) : (unsigned short)0;
        o0.w = (i + 3 < len) ? f2bf(__expf(bf2f(u0.w) - m) * inv) : (unsigned short)0;
        o1.x = (i + 4 < len) ? f2bf(__expf(bf2f(u1.x) - m) * inv) : (unsigned short)0;
        o1.y = (i + 5 < len) ? f2bf(__expf(bf2f(u1.y) - m) * inv) : (unsigned short)0;
        o1.z = (i + 6 < len) ? f2bf(__expf(bf2f(u1.z) - m) * inv) : (unsigned short)0;
        o1.w = (i + 7 < len) ? f2bf(__expf(bf2f(u1.w) - m) * inv) : (unsigned short)0;
        ((ushort4*)p)[i8 * 2]     = o0;
        ((ushort4*)p)[i8 * 2 + 1] = o1;
    }
}

// ---------------- launch ----------------
extern "C" void kernel_launch(void* const* d_in, const int* in_sizes, int n_in,
                              void* d_out, int out_size, void* d_ws, size_t ws_size,
                              hipStream_t stream) {
    constexpr size_t NX = (size_t)NB * SS * DD;   // 8388608
    constexpr size_t NW = (size_t)DD * DD;        // 1048576

    const float* q   = (const float*)d_in[0];
    const float* k   = (const float*)d_in[1];
    const float* v   = (const float*)d_in[2];
    const float* w_q = (const float*)d_in[4];
    const float* b_q = (const float*)d_in[5];
    const float* w_k = (const float*)d_in[6];
    const float* b_k = (const float*)d_in[7];
    const float* w_v = (const float*)d_in[8];
    const float* b_v = (const float*)d_in[9];
    float* out = (float*)d_out;

    char* ws = (char*)d_ws;
    size_t off = 0;
    auto take = [&](size_t bytes) { char* p = ws + off; off += (bytes + 255) & ~(size_t)255; return p; };
    unsigned short* qb  = (unsigned short*)take(NX * 2);
    unsigned short* kb  = (unsigned short*)take(NX * 2);
    unsigned short* vb  = (unsigned short*)take(NX * 2);
    unsigned short* wqb = (unsigned short*)take(NW * 2);
    unsigned short* wkb = (unsigned short*)take(NW * 2);
    unsigned short* wvb = (unsigned short*)take(NW * 2);
    unsigned short* QKV = (unsigned short*)take(NX * 2 * 3);   // Qp | Kp | VpT
    unsigned short* Sb  = (unsigned short*)take((size_t)NB * SS * SS * 2);
    unsigned short* P   = (unsigned short*)take((size_t)NB * SS * SS * 2);
    unsigned short* Qp  = QKV;
    unsigned short* Kp  = QKV + NX;
    unsigned short* VpT = QKV + 2 * NX;           // [b][d][s]

    dim3 blk(256);
    // PV split-K accumulates only into rows >= 1024 of each batch
    for (int b = 0; b < NB; ++b)
        hipMemsetAsync(out + ((size_t)b * SS + 1024) * DD, 0, (size_t)1024 * DD * 4, stream);
    cvt3<<<dim3(NX / 4 / 256, 3), blk, 0, stream>>>(q, k, v, qb, kb, vb, (int)(NX / 4));
    cvt3<<<dim3(NW / 4 / 256, 3), blk, 0, stream>>>(w_q, w_k, w_v, wqb, wkb, wvb, (int)(NW / 4));

    // merged projections: M=8192, N=1024, K=1024; bf16 A (proven 912 TF path)
    gemm_bt<0><<<dim3(8, 64, 3), blk, 0, stream>>>(
        qb, wqb, b_q, kb, wkb, b_k, vb, wvb, b_v, QKV);

    // scores: exact triangular grid, 544 = 4 batches x 136 tiles
    gemm_bt<2><<<dim3(544), blk, 0, stream>>>(
        Qp, Kp, nullptr, nullptr, nullptr, nullptr, nullptr, nullptr, nullptr, Sb);

    softmax_causal<<<dim3(NB * SS), blk, 0, stream>>>(Sb, P);

    // PV: balanced-triple flat grid (768 = 3 layers x 256)
    gemm_bt<3><<<dim3(768), blk, 0, stream>>>(
        P, VpT, nullptr, nullptr, nullptr, nullptr, nullptr, nullptr, nullptr, out);
}

// Round 16
// 175.943 us; speedup vs baseline: 1.3125x; 1.0675x over previous
//
#include <hip/hip_runtime.h>
#include <hip/hip_bf16.h>

// B=4, S=2048, D=1024; fp32 in/out, bf16 MFMA compute.
// R16 = R11 restored verbatim (best measured config, 176.4us):
// fused fp32->bf16 proj (reads inputs once; beats unfused 56+25+hidden ~15us
// L2-writeback serialization -- confirmed twice, R10/R15), triangular 544
// scores grid, PV balanced triples, launch_bounds(256,3).
#define SS 2048
#define DD 1024
#define NB 4

typedef __attribute__((ext_vector_type(8))) short  bf8;    // 8 x bf16
typedef __attribute__((ext_vector_type(4))) float  f32x4;

static __device__ __forceinline__ unsigned short f2bf(float f) {
    unsigned u = __float_as_uint(f);
    u += 0x7fffu + ((u >> 16) & 1u);          // round-to-nearest-even
    return (unsigned short)(u >> 16);
}
static __device__ __forceinline__ float bf2f(unsigned short u) {
    return __uint_as_float((unsigned)u << 16);
}
static __device__ __forceinline__ unsigned short f2bf_hw(float f) {
    union { __hip_bfloat16 h; unsigned short s; } u;
    u.h = __float2bfloat16(f);                // HW v_cvt (RNE), compiler packs
    return u.s;
}

static __device__ __forceinline__ void gload_lds16(const void* g, void* lds) {
    __builtin_amdgcn_global_load_lds((__attribute__((address_space(1))) void*)g,
                                     (__attribute__((address_space(3))) void*)lds,
                                     16, 0, 0);
}

// ---------------- fp32 -> bf16 convert (weights only) ----------------
__global__ __launch_bounds__(256)
void cvt3(const float* __restrict__ a, const float* __restrict__ b, const float* __restrict__ c,
          unsigned short* __restrict__ oa, unsigned short* __restrict__ ob,
          unsigned short* __restrict__ oc, int n4) {
    int i = blockIdx.x * 256 + threadIdx.x;
    if (i >= n4) return;
    const float* in = blockIdx.y == 0 ? a : blockIdx.y == 1 ? b : c;
    unsigned short* out = blockIdx.y == 0 ? oa : blockIdx.y == 1 ? ob : oc;
    float4 v = ((const float4*)in)[i];
    ushort4 o;
    o.x = f2bf(v.x); o.y = f2bf(v.y); o.z = f2bf(v.z); o.w = f2bf(v.w);
    ((ushort4*)out)[i] = o;
}

// ---------------- 128x128 BK=64 bt-GEMM, T2-swizzled LDS ----------------
// MODE 0: merged QKV proj, A = fp32 (fused cvt); z==2 -> transposed store
// MODE 2: scores = Q.K^T/32 -> bf16, exact triangular grid (flat 544)
// MODE 3: PV, fp32 out, causal K-limit, balanced-triple flat grid (768)
#define BM 128
#define BN 128
#define BK 64

template<int MODE>
__global__ __launch_bounds__(256, 3)
void gemm_bt(const void* __restrict__ A0v, const unsigned short* __restrict__ B0p,
             const float* __restrict__ bias0,
             const void* __restrict__ A1v, const unsigned short* __restrict__ B1p,
             const float* __restrict__ bias1,
             const void* __restrict__ A2v, const unsigned short* __restrict__ B2p,
             const float* __restrict__ bias2,
             void* __restrict__ Cout)
{
    constexpr int LDA = (MODE == 3) ? 2048 : 1024;
    constexpr int LDB = (MODE == 3) ? 2048 : 1024;

    int bx, by, bz;
    int qt = 0, nsp = 1, seg = 0;
    if (MODE == 2) {
        // flat 544 = 8*68; bijective XCD chunking, triangular decode
        int f  = (int)blockIdx.x;
        int f2 = (f & 7) * 68 + (f >> 3);
        bz = f2 / 136;
        int r = f2 - bz * 136;
        by = (int)((__fsqrt_rn(8.f * (float)r + 1.f) - 1.f) * 0.5f);
        if (by > 15) by = 15;
        while ((by + 1) * (by + 2) / 2 <= r) ++by;
        while (by * (by + 1) / 2 > r) --by;
        bx = r - by * (by + 1) / 2;
    } else if (MODE == 3) {
        // balanced triples: 3 layers x 256 (b,xt,t); each triple = 2176 rows
        // entry e = qt | seg<<4 | split<<5, packed 6b x 8 per layer
        constexpr unsigned long long T0 = 7ull | 63ull << 6 | 46ull << 12 | 62ull << 18 |
                                          45ull << 24 | 61ull << 30 | 60ull << 36 | 43ull << 42;
        constexpr unsigned long long T1 = 47ull | 6ull << 6 | 44ull << 12 | 42ull << 18 |
                                          4ull << 24 | 58ull << 30 | 5ull << 36 | 59ull << 42;
        constexpr unsigned long long T2 = 0ull | 1ull << 6 | 2ull << 12 | 3ull << 18 |
                                          41ull << 24 | 40ull << 30 | 56ull << 36 | 57ull << 42;
        int f = (int)blockIdx.x;              // 0..767
        int layer = f >> 8, ti = f & 255;
        bz = ti >> 6;                          // batch
        bx = (ti >> 3) & 7;                    // d-tile
        int t = ti & 7;
        unsigned long long tab = layer == 0 ? T0 : layer == 1 ? T1 : T2;
        int e = (int)((tab >> (t * 6)) & 63);
        qt  = e & 15;
        seg = (e >> 4) & 1;
        nsp = ((e >> 5) & 1) ? 2 : 1;
        by  = 0;                               // unused
    } else {
        constexpr int GX  = 8;
        constexpr int CPX = 512 >> 3;
        int f  = (int)blockIdx.y * GX + (int)blockIdx.x;
        int f2 = (f & 7) * CPX + (f >> 3);
        bx = f2 % GX; by = f2 / GX;
        bz = blockIdx.z;
    }

    const float* Af = nullptr;              // MODE 0: fp32 A
    const unsigned short* Ab = nullptr;     // MODE 2/3: bf16 A
    const unsigned short* Bm;
    const float* bias = nullptr;
    int len;
    if (MODE == 0) {
        Af   = ((const float*)(bz == 0 ? A0v : bz == 1 ? A1v : A2v)) + (size_t)by * BM * LDA;
        Bm   = (bz == 0 ? B0p : bz == 1 ? B1p : B2p) + (size_t)bx * BN * LDB;
        bias = bz == 0 ? bias0 : bz == 1 ? bias1 : bias2;
        len  = 1024;
    } else if (MODE == 2) {
        Ab  = (const unsigned short*)A0v + (size_t)bz * SS * DD + (size_t)by * BM * LDA;
        Bm  = B0p + (size_t)bz * SS * DD + (size_t)bx * BN * LDB;
        len = 1024;
    } else {
        int ktot = (qt + 1) * 128, hk = ktot >> 1;       // hk multiple of 64
        int kst  = (nsp == 2 && seg) ? hk : 0;
        len = (nsp == 1) ? ktot : hk;
        Ab = (const unsigned short*)A0v + (size_t)bz * SS * SS + (size_t)qt * BM * LDA + kst;
        Bm = B0p + (size_t)bz * DD * SS + (size_t)bx * BN * LDB + kst;
    }

    // LDS: A fp32 (32 KB, MODE 0) or bf16 (16 KB); B bf16 16 KB
    constexpr int ABYTES = (MODE == 0) ? 32768 : 16384;
    __shared__ __align__(16) char AsB[ABYTES];
    __shared__ __align__(16) unsigned short Bs[BN * BK];

    const int t = threadIdx.x;
    const int l = t & 63;
    const int w = t >> 6;
    const int wr = w >> 1, wc = w & 1;

    // bf16 staging: LDS[r][s] = G[r][s ^ (r&7)] (16B-chunk involution)
    const int srow0 = t >> 3;
    const int sswz  = (t & 7) ^ ((t >> 3) & 7);

    f32x4 zero = {0.f, 0.f, 0.f, 0.f};
    f32x4 acc[4][4];
    #pragma unroll
    for (int i = 0; i < 4; i++)
        #pragma unroll
        for (int j = 0; j < 4; j++) acc[i][j] = zero;

    const int ar = wr * 64 + (l & 15);          // A fragment row
    const int br = wc * 64 + (l & 15);          // B fragment row (output col)
    const int j0 = l >> 4;                      // base chunk (ks adds 4)

    for (int kk = 0; kk < len; kk += BK) {
        if (MODE == 0) {
            // fp32 A: 32 segs of 1KB; seg covers 4 rows x 16 chunks(16B).
            // LDS chunk q=r*16+c holds G[r][c ^ swz(r)], swz=((r&7)<<1)|((r>>3)&1)
            #pragma unroll
            for (int j = 0; j < 8; ++j) {
                int sg = w * 8 + j;
                int r  = sg * 4 + (l >> 4);
                int sz = ((r & 7) << 1) | ((r >> 3) & 1);
                int cg = (l & 15) ^ sz;
                gload_lds16(Af + (size_t)r * LDA + kk + cg * 4,
                            AsB + (size_t)(sg * 64 + l) * 16);
            }
        } else {
            #pragma unroll
            for (int j = 0; j < 4; ++j) {
                int r = srow0 + 32 * j;
                gload_lds16(Ab + (size_t)r * LDA + kk + sswz * 8,
                            AsB + (t + 256 * j) * 16);
            }
        }
        #pragma unroll
        for (int j = 0; j < 4; ++j) {
            int r = srow0 + 32 * j;
            gload_lds16(Bm + (size_t)r * LDB + kk + sswz * 8,
                        (char*)Bs + (t + 256 * j) * 16);
        }
        __syncthreads();
        #pragma unroll
        for (int ks = 0; ks < 2; ++ks) {
            bf8 af[4], bfr[4];
            #pragma unroll
            for (int i = 0; i < 4; i++) {
                int r = ar + i * 16;
                if (MODE == 0) {
                    int sz = ((r & 7) << 1) | ((r >> 3) & 1);
                    int c0 = ks * 8 + j0 * 2;            // 16 chunks of 4 fp32
                    const char* rowb = AsB + (size_t)r * 256;
                    f32x4 lo = *(const f32x4*)(rowb + ((c0)     ^ sz) * 16);
                    f32x4 hi = *(const f32x4*)(rowb + ((c0 + 1) ^ sz) * 16);
                    bf8 vv;
                    vv[0] = (short)f2bf_hw(lo[0]); vv[1] = (short)f2bf_hw(lo[1]);
                    vv[2] = (short)f2bf_hw(lo[2]); vv[3] = (short)f2bf_hw(lo[3]);
                    vv[4] = (short)f2bf_hw(hi[0]); vv[5] = (short)f2bf_hw(hi[1]);
                    vv[6] = (short)f2bf_hw(hi[2]); vv[7] = (short)f2bf_hw(hi[3]);
                    af[i] = vv;
                } else {
                    af[i] = *(const bf8*)(AsB + (size_t)r * 128 +
                                          (((j0 + ks * 4) ^ (r & 7)) << 4));
                }
            }
            #pragma unroll
            for (int j = 0; j < 4; j++) {
                int r = br + j * 16;
                bfr[j] = *(const bf8*)((char*)Bs + (size_t)r * 128 +
                                       (((j0 + ks * 4) ^ (r & 7)) << 4));
            }
            #pragma unroll
            for (int i = 0; i < 4; i++)
                #pragma unroll
                for (int j = 0; j < 4; j++)
                    acc[i][j] = __builtin_amdgcn_mfma_f32_16x16x32_bf16(af[i], bfr[j], acc[i][j], 0, 0, 0);
        }
        __syncthreads();
    }

    const int mb = ((MODE == 3) ? qt : by) * BM + wr * 64;
    const int nb = bx * BN + wc * 64;

    if (MODE == 0) {
        float bv[4];
        #pragma unroll
        for (int j = 0; j < 4; j++) bv[j] = bias[nb + j * 16 + (l & 15)];
        if (bz < 2) {
            unsigned short* C = (unsigned short*)Cout + (size_t)bz * NB * SS * DD;
            #pragma unroll
            for (int i = 0; i < 4; i++) {
                int m0 = mb + i * 16 + ((l >> 4) << 2);
                #pragma unroll
                for (int j = 0; j < 4; j++) {
                    int n = nb + j * 16 + (l & 15);
                    #pragma unroll
                    for (int r = 0; r < 4; r++)
                        C[(size_t)(m0 + r) * DD + n] = f2bf(acc[i][j][r] + bv[j]);
                }
            }
        } else {
            // V: per-batch transposed store C[b][n][s]
            unsigned short* C = (unsigned short*)Cout + (size_t)2 * NB * SS * DD;
            int batch = (by * BM) >> 11;
            #pragma unroll
            for (int i = 0; i < 4; i++) {
                int s = (mb - batch * SS) + i * 16 + ((l >> 4) << 2);
                #pragma unroll
                for (int j = 0; j < 4; j++) {
                    int n = nb + j * 16 + (l & 15);
                    ushort4 pk;
                    pk.x = f2bf(acc[i][j][0] + bv[j]);
                    pk.y = f2bf(acc[i][j][1] + bv[j]);
                    pk.z = f2bf(acc[i][j][2] + bv[j]);
                    pk.w = f2bf(acc[i][j][3] + bv[j]);
                    *(ushort4*)&C[(size_t)batch * DD * SS + (size_t)n * SS + s] = pk;
                }
            }
        }
    } else if (MODE == 2) {
        unsigned short* C = (unsigned short*)Cout + (size_t)bz * SS * SS;
        #pragma unroll
        for (int i = 0; i < 4; i++) {
            int m0 = mb + i * 16 + ((l >> 4) << 2);
            #pragma unroll
            for (int j = 0; j < 4; j++) {
                int n = nb + j * 16 + (l & 15);
                #pragma unroll
                for (int r = 0; r < 4; r++)
                    C[(size_t)(m0 + r) * SS + n] = f2bf(acc[i][j][r] * 0.03125f);
            }
        }
    } else {
        float* C = (float*)Cout + (size_t)bz * SS * DD;
        #pragma unroll
        for (int i = 0; i < 4; i++) {
            int m0 = mb + i * 16 + ((l >> 4) << 2);
            #pragma unroll
            for (int j = 0; j < 4; j++) {
                int n = nb + j * 16 + (l & 15);
                if (nsp == 1) {
                    #pragma unroll
                    for (int r = 0; r < 4; r++)
                        C[(size_t)(m0 + r) * DD + n] = acc[i][j][r];
                } else {
                    #pragma unroll
                    for (int r = 0; r < 4; r++)
                        atomicAdd(&C[(size_t)(m0 + r) * DD + n], acc[i][j][r]);
                }
            }
        }
    }
}

// ---------------- causal row softmax: bf16 scores -> bf16 P ----------------
__global__ __launch_bounds__(256)
void softmax_causal(const unsigned short* __restrict__ Sb, unsigned short* __restrict__ P) {
    __shared__ float tm[4], tl[4];
    int row = blockIdx.x;
    int b = row >> 11, q = row & 2047;
    const unsigned short* s = Sb + ((size_t)b * SS + q) * SS;
    unsigned short* p = P + ((size_t)b * SS + q) * SS;
    int len  = q + 1;
    int len8 = len >> 3;
    int wlen = ((q >> 7) + 1) << 7;            // zero-pad to 128 for PV tiles

    float m = -3e38f, lsum = 0.f;
    for (int i8 = threadIdx.x; i8 < len8; i8 += 256) {
        ushort4 u0 = ((const ushort4*)s)[i8 * 2];
        ushort4 u1 = ((const ushort4*)s)[i8 * 2 + 1];
        float v[8] = {bf2f(u0.x), bf2f(u0.y), bf2f(u0.z), bf2f(u0.w),
                      bf2f(u1.x), bf2f(u1.y), bf2f(u1.z), bf2f(u1.w)};
        float cm = v[0];
        #pragma unroll
        for (int e = 1; e < 8; ++e) cm = fmaxf(cm, v[e]);
        float cs = 0.f;
        #pragma unroll
        for (int e = 0; e < 8; ++e) cs += __expf(v[e] - cm);
        float nm = fmaxf(m, cm);
        lsum = lsum * __expf(m - nm) + cs * __expf(cm - nm);
        m = nm;
    }
    for (int i = (len8 << 3) + threadIdx.x; i < len; i += 256) {
        float v = bf2f(s[i]);
        float nm = fmaxf(m, v);
        lsum = lsum * __expf(m - nm) + __expf(v - nm);
        m = nm;
    }
    #pragma unroll
    for (int o = 32; o; o >>= 1) {
        float om = __shfl_xor(m, o);
        float ol = __shfl_xor(lsum, o);
        float nm = fmaxf(m, om);
        lsum = lsum * __expf(m - nm) + ol * __expf(om - nm);
        m = nm;
    }
    if ((threadIdx.x & 63) == 0) { tm[threadIdx.x >> 6] = m; tl[threadIdx.x >> 6] = lsum; }
    __syncthreads();
    {
        float gm = fmaxf(fmaxf(tm[0], tm[1]), fmaxf(tm[2], tm[3]));
        float gl = tl[0] * __expf(tm[0] - gm) + tl[1] * __expf(tm[1] - gm)
                 + tl[2] * __expf(tm[2] - gm) + tl[3] * __expf(tm[3] - gm);
        m = gm; lsum = gl;
    }
    float inv = 1.f / lsum;

    for (int i8 = threadIdx.x; i8 < (wlen >> 3); i8 += 256) {
        int i = i8 << 3;
        ushort4 u0 = ((const ushort4*)s)[i8 * 2];
        ushort4 u1 = ((const ushort4*)s)[i8 * 2 + 1];
        ushort4 o0, o1;
        o0.x = (i     < len) ? f2bf(__expf(bf2f(u0.x) - m) * inv) : (unsigned short)0;
        o0.y = (i + 1 < len) ? f2bf(__expf(bf2f(u0.y) - m) * inv) : (unsigned short)0;
        o0.z = (i + 2 < len) ? f2bf(__expf(bf2f(u0.z) - m) * inv) : (unsigned short)0;
        o0.w = (i + 3 < len) ? f2bf(__expf(bf2f(u0.w) - m) * inv) : (unsigned short)0;
        o1.x = (i + 4 < len) ? f2bf(__expf(bf2f(u1.x) - m) * inv) : (unsigned short)0;
        o1.y = (i + 5 < len) ? f2bf(__expf(bf2f(u1.y) - m) * inv) : (unsigned short)0;
        o1.z = (i + 6 < len) ? f2bf(__expf(bf2f(u1.z) - m) * inv) : (unsigned short)0;
        o1.w = (i + 7 < len) ? f2bf(__expf(bf2f(u1.w) - m) * inv) : (unsigned short)0;
        ((ushort4*)p)[i8 * 2]     = o0;
        ((ushort4*)p)[i8 * 2 + 1] = o1;
    }
}

// ---------------- launch ----------------
extern "C" void kernel_launch(void* const* d_in, const int* in_sizes, int n_in,
                              void* d_out, int out_size, void* d_ws, size_t ws_size,
                              hipStream_t stream) {
    constexpr size_t NX = (size_t)NB * SS * DD;   // 8388608
    constexpr size_t NW = (size_t)DD * DD;        // 1048576

    const float* q   = (const float*)d_in[0];
    const float* k   = (const float*)d_in[1];
    const float* v   = (const float*)d_in[2];
    const float* w_q = (const float*)d_in[4];
    const float* b_q = (const float*)d_in[5];
    const float* w_k = (const float*)d_in[6];
    const float* b_k = (const float*)d_in[7];
    const float* w_v = (const float*)d_in[8];
    const float* b_v = (const float*)d_in[9];
    float* out = (float*)d_out;

    char* ws = (char*)d_ws;
    size_t off = 0;
    auto take = [&](size_t bytes) { char* p = ws + off; off += (bytes + 255) & ~(size_t)255; return p; };
    unsigned short* wqb = (unsigned short*)take(NW * 2);
    unsigned short* wkb = (unsigned short*)take(NW * 2);
    unsigned short* wvb = (unsigned short*)take(NW * 2);
    unsigned short* QKV = (unsigned short*)take(NX * 2 * 3);   // Qp | Kp | VpT
    unsigned short* Sb  = (unsigned short*)take((size_t)NB * SS * SS * 2);  // bf16 scores
    unsigned short* P   = (unsigned short*)take((size_t)NB * SS * SS * 2);  // bf16 probs
    unsigned short* Qp  = QKV;
    unsigned short* Kp  = QKV + NX;
    unsigned short* VpT = QKV + 2 * NX;           // [b][d][s]

    dim3 blk(256);
    // PV split-K accumulates only into rows >= 1024 of each batch
    for (int b = 0; b < NB; ++b)
        hipMemsetAsync(out + ((size_t)b * SS + 1024) * DD, 0, (size_t)1024 * DD * 4, stream);
    cvt3<<<dim3(NW / 4 / 256, 3), blk, 0, stream>>>(w_q, w_k, w_v, wqb, wkb, wvb, (int)(NW / 4));

    // merged projections: M=8192, N=1024, K=1024; A = fp32 inputs (fused cvt)
    gemm_bt<0><<<dim3(8, 64, 3), blk, 0, stream>>>(
        q, wqb, b_q, k, wkb, b_k, v, wvb, b_v, QKV);

    // scores: exact triangular grid, 544 = 4 batches x 136 tiles
    gemm_bt<2><<<dim3(544), blk, 0, stream>>>(
        Qp, Kp, nullptr, nullptr, nullptr, nullptr, nullptr, nullptr, nullptr, Sb);

    softmax_causal<<<dim3(NB * SS), blk, 0, stream>>>(Sb, P);

    // PV: balanced-triple flat grid (768 = 3 layers x 256)
    gemm_bt<3><<<dim3(768), blk, 0, stream>>>(
        P, VpT, nullptr, nullptr, nullptr, nullptr, nullptr, nullptr, nullptr, out);
}